// Round 11
// baseline (1477.008 us; speedup 1.0000x reference)
//
#include <hip/hip_runtime.h>

#define NN    48
#define DD    16
#define HH    256
#define EE    2256
#define BB    32
#define NPRED 8
#define LSTR  56
#define TMAX  7                      // packed tiles/block <= 7 (tA+tB<=94)
#define PQS   1040                   // PQ per-node stride (floats), de-pow2

typedef __attribute__((ext_vector_type(4))) float f32x4;
typedef __attribute__((ext_vector_type(8))) short short8;

__device__ __forceinline__ float bf2f(unsigned short h) {
    union { unsigned u; float f; } v; v.u = ((unsigned)h) << 16; return v.f;
}
__device__ __forceinline__ unsigned short f2bf(float x) {
    union { float f; unsigned u; } v; v.f = x;
    unsigned r = v.u + 0x7fffu + ((v.u >> 16) & 1u);
    return (unsigned short)(r >> 16);
}
struct Split3 { unsigned d0, d1, d2; };
__device__ __forceinline__ Split3 split2(float u0, float u1)
{
    union F { float f; unsigned u; };
    Split3 o;
    F x0, x1; x0.f = u0; x1.f = u1;
    o.d0 = (x0.u >> 16) | (x1.u & 0xffff0000u);
    F h0a, h0b; h0a.u = x0.u & 0xffff0000u; h0b.u = x1.u & 0xffff0000u;
    F e0a, e0b; e0a.f = u0 - h0a.f; e0b.f = u1 - h0b.f;
    o.d1 = (e0a.u >> 16) | (e0b.u & 0xffff0000u);
    F h1a, h1b; h1a.u = e0a.u & 0xffff0000u; h1b.u = e0b.u & 0xffff0000u;
    F e1a, e1b; e1a.f = e0a.f - h1a.f; e1b.f = e0b.f - h1b.f;
    o.d2 = (e1a.u >> 16) | (e1b.u & 0xffff0000u);
    return o;
}
union PackA { unsigned u[4]; short8 s; };

// ---------------------------------------------------------------------------
// Setup (192 blocks).
// ---------------------------------------------------------------------------
__global__ __launch_bounds__(256) void k_setup(
    const float* __restrict__ time_segs,
    const float* __restrict__ edge_types,
    const float* __restrict__ W1,      // (2,32,256)
    const float* __restrict__ W2,      // (2,256,256)
    const float* __restrict__ b1,      // (2,256)
    float* __restrict__ state,
    float* __restrict__ W1T,           // (2,256,32)
    unsigned short* __restrict__ W2f,  // 393216
    float* __restrict__ PQ,
    int* __restrict__ lists,
    int* __restrict__ counts)
{
    const int tid = blockIdx.x * 256 + threadIdx.x;
    const int NT = 192*256;
    for (int i = tid; i < BB*NN*DD; i += NT)
        state[i] = time_segs[i];
    for (int i = tid; i < 2*HH*32; i += NT) {
        const int t = i >> 13, r = i & 8191, h = r >> 5, f = r & 31;
        W1T[i] = W1[(t*32 + f)*HH + h];
    }
    for (int i = tid; i < 2*8*16*64*8; i += NT) {
        const int j  = i & 7, l = (i >> 3) & 63, nt = (i >> 9) & 15;
        const int kt = (i >> 13) & 7, t = (i >> 16) & 1;
        const int k = kt*32 + ((l >> 4) << 3) + j;
        const int n = nt*16 + (l & 15);
        const float w = W2[((size_t)t*HH + k)*HH + n];
        const unsigned short h0 = f2bf(w);  const float r1 = w  - bf2f(h0);
        const unsigned short h1 = f2bf(r1); const float r2 = r1 - bf2f(h1);
        const unsigned short h2 = f2bf(r2);
        const size_t rest = (size_t)kt*8192 + nt*512 + l*8 + j;
        W2f[(size_t)(t*3+0)*65536 + rest] = h0;
        W2f[(size_t)(t*3+1)*65536 + rest] = h1;
        W2f[(size_t)(t*3+2)*65536 + rest] = h2;
    }
    for (int i = tid; i < BB*NN*1024; i += NT) {
        const int c  = i & 255;
        const int pq = (i >> 8) & 1;
        const int t  = (i >> 9) & 1;
        const int nb = i >> 10;
        float v = pq ? b1[t*HH + c] : 0.f;
        #pragma unroll
        for (int f = 0; f < DD; ++f)
            v = fmaf(time_segs[nb*DD + f], W1[(t*32 + pq*16 + f)*HH + c], v);
        PQ[(size_t)nb*PQS + (i & 1023)] = v;
    }
    if (tid < BB*NN) {
        const int b = tid / NN;
        const int n = tid % NN;
        int* lst = lists + tid * LSTR;
        int c = 0;
        for (int s = 0; s < NN; ++s) {
            if (s == n) continue;
            const int e = s * 47 + (n > s ? n - 1 : n);
            if (edge_types[((size_t)b*EE + e)*3 + 1] > 0.5f) lst[c++] = s;
        }
        const int c1 = c;
        for (int s = 0; s < NN; ++s) {
            if (s == n) continue;
            const int e = s * 47 + (n > s ? n - 1 : n);
            if (edge_types[((size_t)b*EE + e)*3 + 2] > 0.5f) lst[c++] = s;
        }
        counts[tid*2 + 0] = c1;
        counts[tid*2 + 1] = c - c1;
        for (int i = c; i < LSTR; ++i) lst[i] = 0;
    }
}

// ---------------------------------------------------------------------------
// Encoder v4: register-direct A-frags + XCD-clustered swizzle (batches
// 4x..4x+3 -> XCD x, matching k_dec so PQ/node_msg stay XCD-local) +
// two-pass sections (all P/Q loads issue before split/MFMA).
// ---------------------------------------------------------------------------
__global__ __launch_bounds__(256, 2) void k_enc(
    const int*   __restrict__ lists,
    const int*   __restrict__ counts,
    const float* __restrict__ PQ,
    const unsigned short* __restrict__ W2f,
    const float* __restrict__ b2,    // (2,256)
    float* __restrict__ node_msg)
{
    // hw bid h -> XCD h%8; logical lb in [x*96,(x+1)*96) gets h%8==x
    const int lb   = (blockIdx.x & 7)*96 + (blockIdx.x >> 3);
    const int pair = lb % (NN/2);
    const int b    = lb / (NN/2);
    const int n0   = pair * 2;
    const int tid  = threadIdx.x;
    const int lane = tid & 63, wave = tid >> 6;
    const int c8   = (lane >> 4) * 8;

    __shared__ int lst_s[2][LSTR];
    __shared__ int rowinfo[TMAX*16];     // src | g<<8 (g=t*2+nd, 4=pad)
    __shared__ int cnt_s[4];

    for (int i = tid; i < 2*LSTR; i += 256)
        lst_s[i/LSTR][i%LSTR] = lists[(b*NN + n0 + i/LSTR)*LSTR + (i%LSTR)];
    if (tid < 4) cnt_s[tid] = counts[(b*NN + n0 + (tid>>1))*2 + (tid&1)];
    __syncthreads();

    const int c00 = cnt_s[0], c10 = cnt_s[1], c01 = cnt_s[2], c11 = cnt_s[3];
    const int tA  = c00 + c01, tB = c10 + c11;
    const int tAt = (tA + 15) >> 4, tBt = (tB + 15) >> 4;
    const int tiles = tAt + tBt;

    if (tid < TMAX*16) {
        const int r = tid;
        int g = 4, src = 0;
        if (r < tAt*16) {
            if (r < c00)     { src = lst_s[0][r];       g = 0; }
            else if (r < tA) { src = lst_s[1][r - c00]; g = 1; }
        } else if (r < tiles*16) {
            const int s = r - tAt*16;
            if (s < c10)     { src = lst_s[0][c00 + s];       g = 2; }
            else if (s < tB) { src = lst_s[1][c01 + s - c10]; g = 3; }
        }
        rowinfo[r] = src | (g << 8);
    }
    __syncthreads();

    // per-lane precomputed P/Q base offsets (fold src, type, node)
    int psrc[TMAX], qoff[TMAX];
    #pragma unroll
    for (int q = 0; q < TMAX; ++q) {
        const int info = rowinfo[q*16 + (lane & 15)];
        const int src = info & 255;
        const int g   = info >> 8;
        const int nd  = g & 1;
        const int tq  = (g >> 1) & 1;
        psrc[q] = src*PQS + tq*512;
        qoff[q] = (n0 + nd)*PQS + tq*512 + 256;
    }

    f32x4 acc[TMAX][4];
    #pragma unroll
    for (int q = 0; q < TMAX; ++q)
        #pragma unroll
        for (int i = 0; i < 4; ++i)
            acc[q][i] = (f32x4){0.f, 0.f, 0.f, 0.f};

    const float* PQb = PQ + (size_t)b*NN*PQS;

    #pragma unroll 1
    for (int kt = 0; kt < 8; ++kt) {
        const int kc = kt*32 + c8;
        #pragma unroll
        for (int t = 0; t < 2; ++t) {
            const int qlo = t ? tAt : 0;
            const int qhi = t ? tiles : tAt;
            if (qlo == qhi) continue;
            short8 Bf[4][3];
            #pragma unroll
            for (int i = 0; i < 4; ++i)
                #pragma unroll
                for (int p = 0; p < 3; ++p)
                    Bf[i][p] = *(const short8*)(W2f + ((size_t)(t*3+p)*65536
                                 + (size_t)kt*8192 + (wave*4 + i)*512 + lane*8));
            // ---- pass 1: issue all P/Q loads for this section ----
            float4 Pld[TMAX][2], Qld[TMAX][2];
            #pragma unroll
            for (int q = 0; q < TMAX; ++q) {
                if (q >= qlo && q < qhi) {
                    const float* pr = PQb + psrc[q] + kc;
                    Pld[q][0] = *(const float4*)pr;
                    Pld[q][1] = *(const float4*)(pr + 4);
                    const float* qr = PQb + qoff[q] + kc;
                    Qld[q][0] = *(const float4*)qr;
                    Qld[q][1] = *(const float4*)(qr + 4);
                }
            }
            // ---- pass 2: split + MFMA ----
            #pragma unroll
            for (int q = 0; q < TMAX; ++q) {
                if (q >= qlo && q < qhi) {
                    const float4 Pa = Pld[q][0], Pb = Pld[q][1];
                    const float4 Qa = Qld[q][0], Qb = Qld[q][1];
                    const float u0 = fmaxf(Pa.x + Qa.x, 0.f);
                    const float u1 = fmaxf(Pa.y + Qa.y, 0.f);
                    const float u2 = fmaxf(Pa.z + Qa.z, 0.f);
                    const float u3 = fmaxf(Pa.w + Qa.w, 0.f);
                    const float u4 = fmaxf(Pb.x + Qb.x, 0.f);
                    const float u5 = fmaxf(Pb.y + Qb.y, 0.f);
                    const float u6 = fmaxf(Pb.z + Qb.z, 0.f);
                    const float u7 = fmaxf(Pb.w + Qb.w, 0.f);
                    const Split3 s0 = split2(u0, u1);
                    const Split3 s1 = split2(u2, u3);
                    const Split3 s2 = split2(u4, u5);
                    const Split3 s3 = split2(u6, u7);
                    PackA A0, A1, A2;
                    A0.u[0] = s0.d0; A0.u[1] = s1.d0; A0.u[2] = s2.d0; A0.u[3] = s3.d0;
                    A1.u[0] = s0.d1; A1.u[1] = s1.d1; A1.u[2] = s2.d1; A1.u[3] = s3.d1;
                    A2.u[0] = s0.d2; A2.u[1] = s1.d2; A2.u[2] = s2.d2; A2.u[3] = s3.d2;
                    #pragma unroll
                    for (int i = 0; i < 4; ++i) {
                        f32x4 a = acc[q][i];
                        a = __builtin_amdgcn_mfma_f32_16x16x32_bf16(A2.s, Bf[i][0], a, 0, 0, 0);
                        a = __builtin_amdgcn_mfma_f32_16x16x32_bf16(A1.s, Bf[i][1], a, 0, 0, 0);
                        a = __builtin_amdgcn_mfma_f32_16x16x32_bf16(A0.s, Bf[i][2], a, 0, 0, 0);
                        a = __builtin_amdgcn_mfma_f32_16x16x32_bf16(A1.s, Bf[i][0], a, 0, 0, 0);
                        a = __builtin_amdgcn_mfma_f32_16x16x32_bf16(A0.s, Bf[i][1], a, 0, 0, 0);
                        a = __builtin_amdgcn_mfma_f32_16x16x32_bf16(A0.s, Bf[i][0], a, 0, 0, 0);
                        acc[q][i] = a;
                    }
                }
            }
        }
    }

    // ---- readout: relu(acc+b2), per-row node mask, shfl-reduce, store ----
    float b2v[2][4];
    #pragma unroll
    for (int t = 0; t < 2; ++t)
        #pragma unroll
        for (int i = 0; i < 4; ++i)
            b2v[t][i] = b2[t*HH + (wave*4 + i)*16 + (lane & 15)];

    float p0[4], p1[4];
    #pragma unroll
    for (int i = 0; i < 4; ++i) { p0[i] = 0.f; p1[i] = 0.f; }
    #pragma unroll
    for (int q = 0; q < TMAX; ++q) {
        if (q < tiles) {
            const bool secB = (q >= tAt);
            int gv[4];
            #pragma unroll
            for (int rr = 0; rr < 4; ++rr)
                gv[rr] = rowinfo[q*16 + (lane >> 4)*4 + rr] >> 8;
            #pragma unroll
            for (int i = 0; i < 4; ++i) {
                const float bias = secB ? b2v[1][i] : b2v[0][i];
                #pragma unroll
                for (int rr = 0; rr < 4; ++rr) {
                    const float v = fmaxf(acc[q][i][rr] + bias, 0.f);
                    const bool valid = gv[rr] < 4;
                    p0[i] += (valid && !(gv[rr] & 1)) ? v : 0.f;
                    p1[i] += (valid &&  (gv[rr] & 1)) ? v : 0.f;
                }
            }
        }
    }
    #pragma unroll
    for (int i = 0; i < 4; ++i) {
        float v0 = p0[i], v1 = p1[i];
        v0 += __shfl_xor(v0, 16); v0 += __shfl_xor(v0, 32);
        v1 += __shfl_xor(v1, 16); v1 += __shfl_xor(v1, 32);
        if ((lane >> 4) == 0) {
            node_msg[((size_t)(b*NN + n0  ))*HH + (wave*4 + i)*16 + lane] = v0;
            node_msg[((size_t)(b*NN + n0+1))*HH + (wave*4 + i)*16 + lane] = v1;
        }
    }
}

// ---------------------------------------------------------------------------
// Decoder: 8 rows/block (192 blocks), XCD-clustered swizzle matching k_enc.
// Fused 272->256->256->16 + residual + next-step PQ production.
// ---------------------------------------------------------------------------
__global__ __launch_bounds__(256, 2) void k_dec(
    float* __restrict__ state,
    const float* __restrict__ node_msg,
    const float* __restrict__ W1, const float* __restrict__ b1,   // (272,256)
    const float* __restrict__ W2, const float* __restrict__ b2,   // (256,256)
    const float* __restrict__ W3, const float* __restrict__ b3,   // (256,16)
    const float* __restrict__ eW1T,  // (2,256,32)
    const float* __restrict__ eb1,   // (2,256)
    float* __restrict__ PQ,
    float* __restrict__ out, int step)
{
    const int lb   = (blockIdx.x & 7)*24 + (blockIdx.x >> 3);
    const int b    = lb / 6;
    const int row0 = (lb % 6) * 8;
    const int c    = threadIdx.x;

    __shared__ float in_s[8][272];
    __shared__ float d1s[8][HH];
    __shared__ float stn[8][DD];

    for (int i = c; i < 8*272; i += 256) {
        const int m = i / 272, k = i % 272;
        const int r = row0 + m;
        in_s[m][k] = (k < DD)
            ? state[((size_t)b*NN + r)*DD + k]
            : node_msg[((size_t)b*NN + r)*HH + (k - DD)];
    }
    __syncthreads();

    float a0[8];
    {
        const float bb = b1[c];
        #pragma unroll
        for (int m = 0; m < 8; ++m) a0[m] = bb;
        #pragma unroll 2
        for (int k4 = 0; k4 < 68; ++k4) {
            const float* wr = W1 + (k4*4)*HH;
            const float w0=wr[c], w1_=wr[HH+c], w2_=wr[2*HH+c], w3=wr[3*HH+c];
            #pragma unroll
            for (int m = 0; m < 8; ++m) {
                const float4 h = *(const float4*)&in_s[m][k4*4];
                a0[m] = fmaf(h.x,w0, fmaf(h.y,w1_, fmaf(h.z,w2_, fmaf(h.w,w3, a0[m]))));
            }
        }
        #pragma unroll
        for (int m = 0; m < 8; ++m) d1s[m][c] = fmaxf(a0[m], 0.f);
    }
    __syncthreads();
    {
        const float bb = b2[c];
        #pragma unroll
        for (int m = 0; m < 8; ++m) a0[m] = bb;
        #pragma unroll 2
        for (int k4 = 0; k4 < 64; ++k4) {
            const float* wr = W2 + (k4*4)*HH;
            const float w0=wr[c], w1_=wr[HH+c], w2_=wr[2*HH+c], w3=wr[3*HH+c];
            #pragma unroll
            for (int m = 0; m < 8; ++m) {
                const float4 h = *(const float4*)&d1s[m][k4*4];
                a0[m] = fmaf(h.x,w0, fmaf(h.y,w1_, fmaf(h.z,w2_, fmaf(h.w,w3, a0[m]))));
            }
        }
        __syncthreads();
        #pragma unroll
        for (int m = 0; m < 8; ++m) in_s[m][c] = fmaxf(a0[m], 0.f);
    }
    __syncthreads();
    if (c < 128) {
        const int m = c >> 4, cc = c & 15;
        float a = b3[cc];
        #pragma unroll 4
        for (int k4 = 0; k4 < 64; ++k4) {
            const float4 h = *(const float4*)&in_s[m][k4*4];
            a += h.x*W3[(k4*4+0)*16+cc] + h.y*W3[(k4*4+1)*16+cc]
               + h.z*W3[(k4*4+2)*16+cc] + h.w*W3[(k4*4+3)*16+cc];
        }
        const int r = row0 + m;
        const float v = state[((size_t)b*NN + r)*DD + cc] + a;
        state[((size_t)b*NN + r)*DD + cc] = v;
        out[(((size_t)b*NPRED + step)*NN + r)*DD + cc] = v;
        stn[m][cc] = v;
    }
    __syncthreads();
    // ---- fused PQ production: 8 nodes x 1024 ----
    float4 sm[8][4];
    #pragma unroll
    for (int m = 0; m < 8; ++m)
        #pragma unroll
        for (int f4 = 0; f4 < 4; ++f4)
            sm[m][f4] = *(const float4*)&stn[m][f4*4];
    #pragma unroll
    for (int k = 0; k < 4; ++k) {
        const int combo = c + 256*k;           // 0..1023
        const int cc = combo & 255;
        const int pq = (combo >> 8) & 1;
        const int t  = combo >> 9;
        const float* wc = eW1T + ((size_t)t*HH + cc)*32 + pq*16;
        float4 w[4];
        #pragma unroll
        for (int f4 = 0; f4 < 4; ++f4) w[f4] = ((const float4*)wc)[f4];
        const float bias = pq ? eb1[t*HH + cc] : 0.f;
        #pragma unroll
        for (int m = 0; m < 8; ++m) {
            float v = bias;
            #pragma unroll
            for (int f4 = 0; f4 < 4; ++f4) {
                const float4 s = sm[m][f4];
                v = fmaf(s.x,w[f4].x, fmaf(s.y,w[f4].y, fmaf(s.z,w[f4].z, fmaf(s.w,w[f4].w, v))));
            }
            PQ[(size_t)(b*NN + row0 + m)*PQS + t*512 + pq*256 + cc] = v;
        }
    }
}

// ---------------------------------------------------------------------------
extern "C" void kernel_launch(void* const* d_in, const int* in_sizes, int n_in,
                              void* d_out, int out_size, void* d_ws, size_t ws_size,
                              hipStream_t stream)
{
    const float* time_segs  = (const float*)d_in[0];
    const float* edge_types = (const float*)d_in[1];
    const float* enc_W1 = (const float*)d_in[4];
    const float* enc_b1 = (const float*)d_in[5];
    const float* enc_W2 = (const float*)d_in[6];
    const float* enc_b2 = (const float*)d_in[7];
    const float* dec_W1 = (const float*)d_in[8];
    const float* dec_b1 = (const float*)d_in[9];
    const float* dec_W2 = (const float*)d_in[10];
    const float* dec_b2 = (const float*)d_in[11];
    const float* out_W  = (const float*)d_in[12];
    const float* out_b  = (const float*)d_in[13];
    float* out = (float*)d_out;

    float* state    = (float*)d_ws;                    // 24576 f
    float* node_msg = state + BB*NN*DD;                // 393216 f
    float* W1T      = node_msg + BB*NN*HH;             // 16384 f
    unsigned short* W2f = (unsigned short*)(W1T + 2*HH*32);   // 393216 us
    int*   lists    = (int*)(W2f + 2*3*65536);         // 86016 i
    int*   counts   = lists + BB*NN*LSTR;              // 3072 i
    float* PQ       = (float*)(counts + BB*NN*2);      // 1597440 f

    k_setup<<<192, 256, 0, stream>>>(time_segs, edge_types, enc_W1, enc_W2,
                                     enc_b1, state, W1T, W2f, PQ, lists, counts);
    for (int stp = 0; stp < NPRED; ++stp) {
        k_enc<<<BB*(NN/2), 256, 0, stream>>>(lists, counts, PQ, W2f,
                                             enc_b2, node_msg);
        k_dec<<<BB*6, 256, 0, stream>>>(state, node_msg,
                                        dec_W1, dec_b1, dec_W2, dec_b2,
                                        out_W, out_b, W1T, enc_b1, PQ, out, stp);
    }
}

// Round 12
// 814.011 us; speedup vs baseline: 1.8145x; 1.8145x over previous
//
#include <hip/hip_runtime.h>

#define NN    48
#define DD    16
#define HH    256
#define EE    2256
#define BB    32
#define NPRED 8
#define LSTR  56
#define TMAX  7                      // packed tiles/block <= 7 (tA+tB<=94)
#define PQS   1040                   // PQ per-node stride (floats), de-pow2

typedef __attribute__((ext_vector_type(4))) float f32x4;
typedef __attribute__((ext_vector_type(8))) short short8;

__device__ __forceinline__ float bf2f(unsigned short h) {
    union { unsigned u; float f; } v; v.u = ((unsigned)h) << 16; return v.f;
}
__device__ __forceinline__ unsigned short f2bf(float x) {
    union { float f; unsigned u; } v; v.f = x;
    unsigned r = v.u + 0x7fffu + ((v.u >> 16) & 1u);
    return (unsigned short)(r >> 16);
}
struct Split3 { unsigned d0, d1, d2; };
__device__ __forceinline__ Split3 split2(float u0, float u1)
{
    union F { float f; unsigned u; };
    Split3 o;
    F x0, x1; x0.f = u0; x1.f = u1;
    o.d0 = (x0.u >> 16) | (x1.u & 0xffff0000u);
    F h0a, h0b; h0a.u = x0.u & 0xffff0000u; h0b.u = x1.u & 0xffff0000u;
    F e0a, e0b; e0a.f = u0 - h0a.f; e0b.f = u1 - h0b.f;
    o.d1 = (e0a.u >> 16) | (e0b.u & 0xffff0000u);
    F h1a, h1b; h1a.u = e0a.u & 0xffff0000u; h1b.u = e0b.u & 0xffff0000u;
    F e1a, e1b; e1a.f = e0a.f - h1a.f; e1b.f = e0b.f - h1b.f;
    o.d2 = (e1a.u >> 16) | (e1b.u & 0xffff0000u);
    return o;
}
union PackA { unsigned u[4]; short8 s; };

// ---------------------------------------------------------------------------
// Setup (192 blocks) — unchanged from R11 (PQS destride included).
// ---------------------------------------------------------------------------
__global__ __launch_bounds__(256) void k_setup(
    const float* __restrict__ time_segs,
    const float* __restrict__ edge_types,
    const float* __restrict__ W1,      // (2,32,256)
    const float* __restrict__ W2,      // (2,256,256)
    const float* __restrict__ b1,      // (2,256)
    float* __restrict__ state,
    float* __restrict__ W1T,           // (2,256,32)
    unsigned short* __restrict__ W2f,  // 393216
    float* __restrict__ PQ,
    int* __restrict__ lists,
    int* __restrict__ counts)
{
    const int tid = blockIdx.x * 256 + threadIdx.x;
    const int NT = 192*256;
    for (int i = tid; i < BB*NN*DD; i += NT)
        state[i] = time_segs[i];
    for (int i = tid; i < 2*HH*32; i += NT) {
        const int t = i >> 13, r = i & 8191, h = r >> 5, f = r & 31;
        W1T[i] = W1[(t*32 + f)*HH + h];
    }
    for (int i = tid; i < 2*8*16*64*8; i += NT) {
        const int j  = i & 7, l = (i >> 3) & 63, nt = (i >> 9) & 15;
        const int kt = (i >> 13) & 7, t = (i >> 16) & 1;
        const int k = kt*32 + ((l >> 4) << 3) + j;
        const int n = nt*16 + (l & 15);
        const float w = W2[((size_t)t*HH + k)*HH + n];
        const unsigned short h0 = f2bf(w);  const float r1 = w  - bf2f(h0);
        const unsigned short h1 = f2bf(r1); const float r2 = r1 - bf2f(h1);
        const unsigned short h2 = f2bf(r2);
        const size_t rest = (size_t)kt*8192 + nt*512 + l*8 + j;
        W2f[(size_t)(t*3+0)*65536 + rest] = h0;
        W2f[(size_t)(t*3+1)*65536 + rest] = h1;
        W2f[(size_t)(t*3+2)*65536 + rest] = h2;
    }
    for (int i = tid; i < BB*NN*1024; i += NT) {
        const int c  = i & 255;
        const int pq = (i >> 8) & 1;
        const int t  = (i >> 9) & 1;
        const int nb = i >> 10;
        float v = pq ? b1[t*HH + c] : 0.f;
        #pragma unroll
        for (int f = 0; f < DD; ++f)
            v = fmaf(time_segs[nb*DD + f], W1[(t*32 + pq*16 + f)*HH + c], v);
        PQ[(size_t)nb*PQS + (i & 1023)] = v;
    }
    if (tid < BB*NN) {
        const int b = tid / NN;
        const int n = tid % NN;
        int* lst = lists + tid * LSTR;
        int c = 0;
        for (int s = 0; s < NN; ++s) {
            if (s == n) continue;
            const int e = s * 47 + (n > s ? n - 1 : n);
            if (edge_types[((size_t)b*EE + e)*3 + 1] > 0.5f) lst[c++] = s;
        }
        const int c1 = c;
        for (int s = 0; s < NN; ++s) {
            if (s == n) continue;
            const int e = s * 47 + (n > s ? n - 1 : n);
            if (edge_types[((size_t)b*EE + e)*3 + 2] > 0.5f) lst[c++] = s;
        }
        counts[tid*2 + 0] = c1;
        counts[tid*2 + 1] = c - c1;
        for (int i = c; i < LSTR; ++i) lst[i] = 0;
    }
}

// ---------------------------------------------------------------------------
// Encoder v5: R10's single-pass register-direct structure, n-dim split
// across 2 blocks (grid 1536): wave owns 2 n-tiles -> acc[7][2]=56 AGPR,
// Bf[2][3]=24 VGPR -> ~150 combined -> 3 waves/SIMD (launch_bounds 256,3).
// XCD-clustered swizzle: lb in [x*192,(x+1)*192) -> XCD x (4 batches/XCD).
// ---------------------------------------------------------------------------
__global__ __launch_bounds__(256, 3) void k_enc(
    const int*   __restrict__ lists,
    const int*   __restrict__ counts,
    const float* __restrict__ PQ,
    const unsigned short* __restrict__ W2f,
    const float* __restrict__ b2,    // (2,256)
    float* __restrict__ node_msg)
{
    const int lb   = (blockIdx.x & 7)*192 + (blockIdx.x >> 3);
    const int half = lb & 1;             // which 128-col half of the output
    const int pair = (lb >> 1) % (NN/2);
    const int b    = lb / NN;            // lb/48
    const int n0   = pair * 2;
    const int tid  = threadIdx.x;
    const int lane = tid & 63, wave = tid >> 6;
    const int c8   = (lane >> 4) * 8;

    __shared__ int lst_s[2][LSTR];
    __shared__ int rowinfo[TMAX*16];     // src | g<<8 (g=t*2+nd, 4=pad)
    __shared__ int cnt_s[4];

    for (int i = tid; i < 2*LSTR; i += 256)
        lst_s[i/LSTR][i%LSTR] = lists[(b*NN + n0 + i/LSTR)*LSTR + (i%LSTR)];
    if (tid < 4) cnt_s[tid] = counts[(b*NN + n0 + (tid>>1))*2 + (tid&1)];
    __syncthreads();

    const int c00 = cnt_s[0], c10 = cnt_s[1], c01 = cnt_s[2], c11 = cnt_s[3];
    const int tA  = c00 + c01, tB = c10 + c11;
    const int tAt = (tA + 15) >> 4, tBt = (tB + 15) >> 4;
    const int tiles = tAt + tBt;

    if (tid < TMAX*16) {
        const int r = tid;
        int g = 4, src = 0;
        if (r < tAt*16) {
            if (r < c00)     { src = lst_s[0][r];       g = 0; }
            else if (r < tA) { src = lst_s[1][r - c00]; g = 1; }
        } else if (r < tiles*16) {
            const int s = r - tAt*16;
            if (s < c10)     { src = lst_s[0][c00 + s];       g = 2; }
            else if (s < tB) { src = lst_s[1][c01 + s - c10]; g = 3; }
        }
        rowinfo[r] = src | (g << 8);
    }
    __syncthreads();

    // per-lane build metadata (row = lane&15 within each tile)
    int bsrc[TMAX], bnd[TMAX];
    #pragma unroll
    for (int q = 0; q < TMAX; ++q) {
        const int info = rowinfo[q*16 + (lane & 15)];
        bsrc[q] = info & 255;
        bnd[q]  = (info >> 8) & 1;
    }

    f32x4 acc[TMAX][2];
    #pragma unroll
    for (int q = 0; q < TMAX; ++q) {
        acc[q][0] = (f32x4){0.f, 0.f, 0.f, 0.f};
        acc[q][1] = (f32x4){0.f, 0.f, 0.f, 0.f};
    }

    const float* PQb = PQ + (size_t)b*NN*PQS;
    const int ntb = half*8 + wave*2;     // this wave's first n-tile

    #pragma unroll 1
    for (int kt = 0; kt < 8; ++kt) {
        const int kc = kt*32 + c8;
        #pragma unroll
        for (int t = 0; t < 2; ++t) {
            const int qlo = t ? tAt : 0;
            const int qhi = t ? tiles : tAt;
            if (qlo == qhi) continue;
            // B fragments for this wave's 2 n-tiles
            short8 Bf[2][3];
            #pragma unroll
            for (int i = 0; i < 2; ++i)
                #pragma unroll
                for (int p = 0; p < 3; ++p)
                    Bf[i][p] = *(const short8*)(W2f + ((size_t)(t*3+p)*65536
                                 + (size_t)kt*8192 + (ntb + i)*512 + lane*8));
            // Q rows for both nodes at this lane's col group
            const float* qp = PQb + n0*PQS + t*512 + 256 + kc;
            const float4 Q0a = *(const float4*)qp,       Q0b = *(const float4*)(qp+4);
            const float4 Q1a = *(const float4*)(qp+PQS), Q1b = *(const float4*)(qp+PQS+4);
            #pragma unroll
            for (int q = 0; q < TMAX; ++q) {
                if (q >= qlo && q < qhi) {
                    const float* pr = PQb + bsrc[q]*PQS + t*512 + kc;
                    const float4 Pa = *(const float4*)pr, Pb = *(const float4*)(pr+4);
                    const int nd = bnd[q];
                    const float u0 = fmaxf(Pa.x + (nd ? Q1a.x : Q0a.x), 0.f);
                    const float u1 = fmaxf(Pa.y + (nd ? Q1a.y : Q0a.y), 0.f);
                    const float u2 = fmaxf(Pa.z + (nd ? Q1a.z : Q0a.z), 0.f);
                    const float u3 = fmaxf(Pa.w + (nd ? Q1a.w : Q0a.w), 0.f);
                    const float u4 = fmaxf(Pb.x + (nd ? Q1b.x : Q0b.x), 0.f);
                    const float u5 = fmaxf(Pb.y + (nd ? Q1b.y : Q0b.y), 0.f);
                    const float u6 = fmaxf(Pb.z + (nd ? Q1b.z : Q0b.z), 0.f);
                    const float u7 = fmaxf(Pb.w + (nd ? Q1b.w : Q0b.w), 0.f);
                    const Split3 s0 = split2(u0, u1);
                    const Split3 s1 = split2(u2, u3);
                    const Split3 s2 = split2(u4, u5);
                    const Split3 s3 = split2(u6, u7);
                    PackA A0, A1, A2;
                    A0.u[0] = s0.d0; A0.u[1] = s1.d0; A0.u[2] = s2.d0; A0.u[3] = s3.d0;
                    A1.u[0] = s0.d1; A1.u[1] = s1.d1; A1.u[2] = s2.d1; A1.u[3] = s3.d1;
                    A2.u[0] = s0.d2; A2.u[1] = s1.d2; A2.u[2] = s2.d2; A2.u[3] = s3.d2;
                    #pragma unroll
                    for (int i = 0; i < 2; ++i) {
                        f32x4 a = acc[q][i];
                        a = __builtin_amdgcn_mfma_f32_16x16x32_bf16(A2.s, Bf[i][0], a, 0, 0, 0);
                        a = __builtin_amdgcn_mfma_f32_16x16x32_bf16(A1.s, Bf[i][1], a, 0, 0, 0);
                        a = __builtin_amdgcn_mfma_f32_16x16x32_bf16(A0.s, Bf[i][2], a, 0, 0, 0);
                        a = __builtin_amdgcn_mfma_f32_16x16x32_bf16(A1.s, Bf[i][0], a, 0, 0, 0);
                        a = __builtin_amdgcn_mfma_f32_16x16x32_bf16(A0.s, Bf[i][1], a, 0, 0, 0);
                        a = __builtin_amdgcn_mfma_f32_16x16x32_bf16(A0.s, Bf[i][0], a, 0, 0, 0);
                        acc[q][i] = a;
                    }
                }
            }
        }
    }

    // ---- readout: relu(acc+b2), per-row node mask, shfl-reduce, store ----
    float b2v[2][2];
    #pragma unroll
    for (int t = 0; t < 2; ++t)
        #pragma unroll
        for (int i = 0; i < 2; ++i)
            b2v[t][i] = b2[t*HH + (ntb + i)*16 + (lane & 15)];

    float p0[2], p1[2];
    p0[0] = p0[1] = p1[0] = p1[1] = 0.f;
    #pragma unroll
    for (int q = 0; q < TMAX; ++q) {
        if (q < tiles) {
            const bool secB = (q >= tAt);
            int gv[4];
            #pragma unroll
            for (int rr = 0; rr < 4; ++rr)
                gv[rr] = rowinfo[q*16 + (lane >> 4)*4 + rr] >> 8;
            #pragma unroll
            for (int i = 0; i < 2; ++i) {
                const float bias = secB ? b2v[1][i] : b2v[0][i];
                #pragma unroll
                for (int rr = 0; rr < 4; ++rr) {
                    const float v = fmaxf(acc[q][i][rr] + bias, 0.f);
                    const bool valid = gv[rr] < 4;
                    p0[i] += (valid && !(gv[rr] & 1)) ? v : 0.f;
                    p1[i] += (valid &&  (gv[rr] & 1)) ? v : 0.f;
                }
            }
        }
    }
    #pragma unroll
    for (int i = 0; i < 2; ++i) {
        float v0 = p0[i], v1 = p1[i];
        v0 += __shfl_xor(v0, 16); v0 += __shfl_xor(v0, 32);
        v1 += __shfl_xor(v1, 16); v1 += __shfl_xor(v1, 32);
        if ((lane >> 4) == 0) {
            node_msg[((size_t)(b*NN + n0  ))*HH + (ntb + i)*16 + lane] = v0;
            node_msg[((size_t)(b*NN + n0+1))*HH + (ntb + i)*16 + lane] = v1;
        }
    }
}

// ---------------------------------------------------------------------------
// Decoder: 8 rows/block (192 blocks), XCD-clustered swizzle, fused PQ.
// Unchanged from R11 (not in hot top-5).
// ---------------------------------------------------------------------------
__global__ __launch_bounds__(256, 2) void k_dec(
    float* __restrict__ state,
    const float* __restrict__ node_msg,
    const float* __restrict__ W1, const float* __restrict__ b1,   // (272,256)
    const float* __restrict__ W2, const float* __restrict__ b2,   // (256,256)
    const float* __restrict__ W3, const float* __restrict__ b3,   // (256,16)
    const float* __restrict__ eW1T,  // (2,256,32)
    const float* __restrict__ eb1,   // (2,256)
    float* __restrict__ PQ,
    float* __restrict__ out, int step)
{
    const int lb   = (blockIdx.x & 7)*24 + (blockIdx.x >> 3);
    const int b    = lb / 6;
    const int row0 = (lb % 6) * 8;
    const int c    = threadIdx.x;

    __shared__ float in_s[8][272];
    __shared__ float d1s[8][HH];
    __shared__ float stn[8][DD];

    for (int i = c; i < 8*272; i += 256) {
        const int m = i / 272, k = i % 272;
        const int r = row0 + m;
        in_s[m][k] = (k < DD)
            ? state[((size_t)b*NN + r)*DD + k]
            : node_msg[((size_t)b*NN + r)*HH + (k - DD)];
    }
    __syncthreads();

    float a0[8];
    {
        const float bb = b1[c];
        #pragma unroll
        for (int m = 0; m < 8; ++m) a0[m] = bb;
        #pragma unroll 2
        for (int k4 = 0; k4 < 68; ++k4) {
            const float* wr = W1 + (k4*4)*HH;
            const float w0=wr[c], w1_=wr[HH+c], w2_=wr[2*HH+c], w3=wr[3*HH+c];
            #pragma unroll
            for (int m = 0; m < 8; ++m) {
                const float4 h = *(const float4*)&in_s[m][k4*4];
                a0[m] = fmaf(h.x,w0, fmaf(h.y,w1_, fmaf(h.z,w2_, fmaf(h.w,w3, a0[m]))));
            }
        }
        #pragma unroll
        for (int m = 0; m < 8; ++m) d1s[m][c] = fmaxf(a0[m], 0.f);
    }
    __syncthreads();
    {
        const float bb = b2[c];
        #pragma unroll
        for (int m = 0; m < 8; ++m) a0[m] = bb;
        #pragma unroll 2
        for (int k4 = 0; k4 < 64; ++k4) {
            const float* wr = W2 + (k4*4)*HH;
            const float w0=wr[c], w1_=wr[HH+c], w2_=wr[2*HH+c], w3=wr[3*HH+c];
            #pragma unroll
            for (int m = 0; m < 8; ++m) {
                const float4 h = *(const float4*)&d1s[m][k4*4];
                a0[m] = fmaf(h.x,w0, fmaf(h.y,w1_, fmaf(h.z,w2_, fmaf(h.w,w3, a0[m]))));
            }
        }
        __syncthreads();
        #pragma unroll
        for (int m = 0; m < 8; ++m) in_s[m][c] = fmaxf(a0[m], 0.f);
    }
    __syncthreads();
    if (c < 128) {
        const int m = c >> 4, cc = c & 15;
        float a = b3[cc];
        #pragma unroll 4
        for (int k4 = 0; k4 < 64; ++k4) {
            const float4 h = *(const float4*)&in_s[m][k4*4];
            a += h.x*W3[(k4*4+0)*16+cc] + h.y*W3[(k4*4+1)*16+cc]
               + h.z*W3[(k4*4+2)*16+cc] + h.w*W3[(k4*4+3)*16+cc];
        }
        const int r = row0 + m;
        const float v = state[((size_t)b*NN + r)*DD + cc] + a;
        state[((size_t)b*NN + r)*DD + cc] = v;
        out[(((size_t)b*NPRED + step)*NN + r)*DD + cc] = v;
        stn[m][cc] = v;
    }
    __syncthreads();
    float4 sm[8][4];
    #pragma unroll
    for (int m = 0; m < 8; ++m)
        #pragma unroll
        for (int f4 = 0; f4 < 4; ++f4)
            sm[m][f4] = *(const float4*)&stn[m][f4*4];
    #pragma unroll
    for (int k = 0; k < 4; ++k) {
        const int combo = c + 256*k;
        const int cc = combo & 255;
        const int pq = (combo >> 8) & 1;
        const int t  = combo >> 9;
        const float* wc = eW1T + ((size_t)t*HH + cc)*32 + pq*16;
        float4 w[4];
        #pragma unroll
        for (int f4 = 0; f4 < 4; ++f4) w[f4] = ((const float4*)wc)[f4];
        const float bias = pq ? eb1[t*HH + cc] : 0.f;
        #pragma unroll
        for (int m = 0; m < 8; ++m) {
            float v = bias;
            #pragma unroll
            for (int f4 = 0; f4 < 4; ++f4) {
                const float4 s = sm[m][f4];
                v = fmaf(s.x,w[f4].x, fmaf(s.y,w[f4].y, fmaf(s.z,w[f4].z, fmaf(s.w,w[f4].w, v))));
            }
            PQ[(size_t)(b*NN + row0 + m)*PQS + t*512 + pq*256 + cc] = v;
        }
    }
}

// ---------------------------------------------------------------------------
extern "C" void kernel_launch(void* const* d_in, const int* in_sizes, int n_in,
                              void* d_out, int out_size, void* d_ws, size_t ws_size,
                              hipStream_t stream)
{
    const float* time_segs  = (const float*)d_in[0];
    const float* edge_types = (const float*)d_in[1];
    const float* enc_W1 = (const float*)d_in[4];
    const float* enc_b1 = (const float*)d_in[5];
    const float* enc_W2 = (const float*)d_in[6];
    const float* enc_b2 = (const float*)d_in[7];
    const float* dec_W1 = (const float*)d_in[8];
    const float* dec_b1 = (const float*)d_in[9];
    const float* dec_W2 = (const float*)d_in[10];
    const float* dec_b2 = (const float*)d_in[11];
    const float* out_W  = (const float*)d_in[12];
    const float* out_b  = (const float*)d_in[13];
    float* out = (float*)d_out;

    float* state    = (float*)d_ws;                    // 24576 f
    float* node_msg = state + BB*NN*DD;                // 393216 f
    float* W1T      = node_msg + BB*NN*HH;             // 16384 f
    unsigned short* W2f = (unsigned short*)(W1T + 2*HH*32);   // 393216 us
    int*   lists    = (int*)(W2f + 2*3*65536);         // 86016 i
    int*   counts   = lists + BB*NN*LSTR;              // 3072 i
    float* PQ       = (float*)(counts + BB*NN*2);      // 1597440 f

    k_setup<<<192, 256, 0, stream>>>(time_segs, edge_types, enc_W1, enc_W2,
                                     enc_b1, state, W1T, W2f, PQ, lists, counts);
    for (int stp = 0; stp < NPRED; ++stp) {
        k_enc<<<BB*NN*2/2, 256, 0, stream>>>(lists, counts, PQ, W2f,
                                             enc_b2, node_msg);
        k_dec<<<BB*6, 256, 0, stream>>>(state, node_msg,
                                        dec_W1, dec_b1, dec_W2, dec_b2,
                                        out_W, out_b, W1T, enc_b1, PQ, out, stp);
    }
}